// Round 10
// baseline (210.731 us; speedup 1.0000x reference)
//
#include <hip/hip_runtime.h>
#include <hip/hip_fp16.h>

// RepulsionNLH: erep_atomic[a] = 0.5*BOHR * sum_{e: src[e]==a} Z[src]*Z[dst]*phi(e)*switch[e]/dist[e]
// phi(e) = sum_k CS[s12][k] * exp(-ALPHAS[s12][k] * dist[e]),  s12 = species[src] + 92*species[dst]
//
// R22: R21 (steal) confirmed: p1 70->61us, total 218->210.2. Remaining p1 cost
// is tab16 L2-gather MSHR throughput (structural: both tables don't fit LDS).
// Two levers this round: (a) p1 cross-chunk SOFTWARE PIPELINE -- first chunk
// = bid (steal counter offset by G), next chunk stolen during the scan phase,
// its stream loads issued after the post-phase-B barrier so their latency
// hides under copy-out; spcL preamble overlaps chunk-0 loads. (b) p2a
// SPLITS 16->32: halves per-block tail on the latency-bound pairs readback.

#define ZMAX_C 92
#define TAB93  93
#define NTAB   (TAB93 * TAB93)   // 8649
#define HALF_BOHR 0.264588605f   // 0.5 * 0.52917721
#define NBMAX 64
#define APB 2048                 // atoms per bucket
#define APB_LOG 11
#define SPLITS 32
#define TPB  1024                // persistent p1 block size (16 waves)
#define NW   (TPB / 64)          // 16 waves
#define TPB2 256                 // p0/p2a block size
#define EPT 8                    // edges per thread in p1
#define BLK_EDGES (TPB * EPT)    // 8192 edges per chunk
#define SPC_CAP 122880           // 120 KB LDS species cache cap

typedef int            ivec4 __attribute__((ext_vector_type(4)));
typedef float          fvec4 __attribute__((ext_vector_type(4)));

#if __has_builtin(__builtin_amdgcn_rcpf)
#define FAST_RCP(x) __builtin_amdgcn_rcpf(x)
#else
#define FAST_RCP(x) (1.0f / (x))
#endif

__device__ __forceinline__ float half_lo(unsigned u) {
    return __half2float(*reinterpret_cast<const __half*>(&u));
}
__device__ __forceinline__ float half_hi(unsigned u) {
    unsigned s = u >> 16;
    return __half2float(*reinterpret_cast<const __half*>(&s));
}

// ---------------- p0: Z-premult f16 table, spc8 bytes, cursors, out zero ----
__global__ __launch_bounds__(TPB2) void p0_prep(
    const float* __restrict__ CS, const float* __restrict__ ALPHAS,
    const int* __restrict__ species,
    uint4* __restrict__ tab16, unsigned char* __restrict__ spc8,
    unsigned* __restrict__ cursor, unsigned* __restrict__ steal,
    float* __restrict__ out, int n_atoms, int nb)
{
    int i = blockIdx.x * TPB2 + threadIdx.x;
    if (i < NTAB) {
        int sd = i / TAB93;
        int ss = i - TAB93 * sd;
        int ref = ss + ZMAX_C * sd;          // reference's (colliding) index
        float Z = (ss > 0 && sd > 0) ? (float)(ss * sd) : 0.0f;
        __half h[8];
        h[0] = __float2half_rn(CS[3*ref+0] * Z);
        h[1] = __float2half_rn(CS[3*ref+1] * Z);
        h[2] = __float2half_rn(CS[3*ref+2] * Z);
        h[3] = __float2half_rn(-ALPHAS[3*ref+0]);
        h[4] = __float2half_rn(-ALPHAS[3*ref+1]);
        h[5] = __float2half_rn(-ALPHAS[3*ref+2]);
        h[6] = __half(0.0f); h[7] = __half(0.0f);
        tab16[i] = *reinterpret_cast<uint4*>(h);
    }
    if (i < n_atoms) {
        spc8[i] = (unsigned char)species[i];
        out[i] = 0.0f;
    }
    if (i < nb) cursor[i] = 0u;
    if (i == 0) *steal = 0u;
}

// stream-load helper: 8 edges/thread (2x 4-wide groups at +0 and +256)
#define LOAD_STREAMS(C, RV, WV, SRCV, DSTV)                                        \
    {                                                                              \
        long long wb_ = (long long)(C) * BLK_EDGES + (long long)wave * (64 * EPT); \
        long long eA_ = wb_ + lane * 4;                                            \
        long long eB_ = wb_ + 256 + lane * 4;                                      \
        if (eB_ + 3 < (long long)n_edges) {                                        \
            fvec4 r4 = *reinterpret_cast<const fvec4*>(dist + eA_);                \
            fvec4 w4 = *reinterpret_cast<const fvec4*>(swt + eA_);                 \
            ivec4 s4 = *reinterpret_cast<const ivec4*>(edge_src + eA_);            \
            ivec4 d4 = *reinterpret_cast<const ivec4*>(edge_dst + eA_);            \
            fvec4 r5 = *reinterpret_cast<const fvec4*>(dist + eB_);                \
            fvec4 w5 = *reinterpret_cast<const fvec4*>(swt + eB_);                 \
            ivec4 s5 = *reinterpret_cast<const ivec4*>(edge_src + eB_);            \
            ivec4 d5 = *reinterpret_cast<const ivec4*>(edge_dst + eB_);            \
            _Pragma("unroll")                                                      \
            for (int k_ = 0; k_ < 4; ++k_) {                                       \
                RV[k_] = r4[k_];     WV[k_] = w4[k_];                              \
                SRCV[k_] = s4[k_];   DSTV[k_] = d4[k_];                            \
                RV[4+k_] = r5[k_];   WV[4+k_] = w5[k_];                            \
                SRCV[4+k_] = s5[k_]; DSTV[4+k_] = d5[k_];                          \
            }                                                                      \
        } else {                                                                   \
            _Pragma("unroll")                                                      \
            for (int k_ = 0; k_ < 4; ++k_) {                                       \
                long long ea_ = eA_ + k_, eb_ = eB_ + k_;                          \
                bool va_ = (ea_ >= 0 && ea_ < (long long)n_edges);                 \
                bool vb_ = (eb_ >= 0 && eb_ < (long long)n_edges);                 \
                RV[k_]   = va_ ? dist[ea_] : 1.f;  WV[k_]   = va_ ? swt[ea_] : 0.f;\
                SRCV[k_] = va_ ? edge_src[ea_] : 0;                                \
                DSTV[k_] = va_ ? edge_dst[ea_] : 0;                                \
                RV[4+k_]   = vb_ ? dist[eb_] : 1.f; WV[4+k_] = vb_ ? swt[eb_] : 0.f;\
                SRCV[4+k_] = vb_ ? edge_src[eb_] : 0;                              \
                DSTV[4+k_] = vb_ ? edge_dst[eb_] : 0;                              \
            }                                                                      \
        }                                                                          \
    }

// ---------------- p1 (persistent, spcL LDS, steal, cross-chunk pipeline) ----
__global__ __launch_bounds__(TPB) void p1_bin_lds(
    const int* __restrict__ edge_src, const int* __restrict__ edge_dst,
    const float* __restrict__ dist, const float* __restrict__ swt,
    const unsigned char* __restrict__ spc8, const uint4* __restrict__ tab16,
    unsigned* __restrict__ pairs, unsigned* __restrict__ cursor,
    unsigned* __restrict__ steal,
    int nb, int cap, int n_edges, int n_atoms, int nchunks)
{
    __shared__ unsigned char spcL[SPC_CAP];  // 120 KB species cache
    __shared__ unsigned stage[BLK_EDGES];    // 32 KB packed {lsrc<<16 | f16}
    __shared__ unsigned histW[NW][NBMAX];    // 4 KB per-wave histogram replicas
    __shared__ unsigned hist[NBMAX];
    __shared__ unsigned lbase[NBMAX];
    __shared__ unsigned gbase[NBMAX];
    __shared__ unsigned bcast;

    int tid = threadIdx.x, bid = blockIdx.x;
    const int G = gridDim.x;
    int lane = tid & 63, wave = tid >> 6;

    // ---- prologue: first chunk = bid (no steal); its stream loads overlap
    // the spcL global->LDS copy below.
    int c = bid;
    float rv[EPT], wv[EPT];
    int srcv[EPT], dstv[EPT];
    if (c < nchunks) LOAD_STREAMS(c, rv, wv, srcv, dstv);

    {
        uint4* dv = (uint4*)spcL;
        const uint4* sv = (const uint4*)spc8;       // buffer 256B-aligned/padded
        int n16 = (n_atoms + 15) >> 4;
        for (int i = tid; i < n16; i += TPB) dv[i] = sv[i];
    }
    ((unsigned*)histW)[tid] = 0u;            // NW*NBMAX == TPB: one slot each
    __syncthreads();                         // spcL + histW ready

    while (c < nchunks) {
        long long wbase = (long long)c * BLK_EDGES + (long long)wave * (64 * EPT);
        unsigned meta[EPT];   // bit31 valid | rank<<17 | b<<11 | lsrc (rank per-wave, <512)
        unsigned short s12r[EPT];

        // species from LDS, s12, tab gathers (overlap phase A below)
        {
            int ssv[EPT], sdv[EPT];
            #pragma unroll
            for (int i = 0; i < EPT; ++i) ssv[i] = spcL[srcv[i]];
            #pragma unroll
            for (int i = 0; i < EPT; ++i) sdv[i] = spcL[dstv[i]];
            #pragma unroll
            for (int i = 0; i < EPT; ++i)
                s12r[i] = (unsigned short)(ssv[i] + TAB93 * sdv[i]);
        }
        uint4 tv[EPT];
        #pragma unroll
        for (int k = 0; k < EPT; ++k) tv[k] = tab16[s12r[k]];

        // ==== phase A: bin (hist atomics overlap the tab gathers in flight) ====
        #pragma unroll
        for (int j = 0; j < EPT / 4; ++j) {
            long long e0 = wbase + j * 256 + lane * 4;
            #pragma unroll
            for (int k = 0; k < 4; ++k) {
                int idx = j * 4 + k;
                meta[idx] = 0u;
                if (e0 + k < (long long)n_edges) {
                    unsigned b    = (unsigned)srcv[idx] >> APB_LOG;
                    unsigned lsrc = (unsigned)srcv[idx] & (APB - 1);
                    unsigned rank = atomicAdd(&histW[wave][b], 1u);   // < 512
                    meta[idx] = 0x80000000u | (rank << 17) | (b << 11) | lsrc;
                }
            }
        }
        __syncthreads();
        // fold wave replicas; scan; reserve; STEAL next chunk
        if (tid == 0) bcast = G + atomicAdd(steal, 1u);
        if (tid < 64) {
            unsigned run = 0;
            #pragma unroll
            for (int w = 0; w < NW; ++w) {
                unsigned t = histW[w][tid];
                histW[w][tid] = run;
                run += t;
            }
            unsigned tot = run;
            if (tid < nb) hist[tid] = tot;
            unsigned v = (tid < nb) ? tot : 0u;
            unsigned x = v;
            #pragma unroll
            for (int off = 1; off < 64; off <<= 1) {
                unsigned y = __shfl_up(x, off);
                if ((tid & 63) >= off) x += y;
            }
            if (tid < nb) {
                lbase[tid] = x - v;
                gbase[tid] = v ? atomicAdd(cursor + tid, v) : 0u;
            }
        }
        __syncthreads();

        // ==== phase B: pure compute + scatter (all operands in registers) ====
        #pragma unroll
        for (int idx = 0; idx < EPT; ++idx) {
            unsigned m = meta[idx];
            if (!(m & 0x80000000u)) continue;
            float c0 = half_lo(tv[idx].x), c1 = half_hi(tv[idx].x);
            float c2 = half_lo(tv[idx].y), na0 = half_hi(tv[idx].y);
            float na1 = half_lo(tv[idx].z), na2 = half_hi(tv[idx].z);
            float r = rv[idx];
            float phi = c0 * __expf(na0 * r)
                      + c1 * __expf(na1 * r)
                      + c2 * __expf(na2 * r);
            float val = HALF_BOHR * phi * wv[idx] * FAST_RCP(r);  // Z premult in c
            unsigned b = (m >> 11) & 63u;
            unsigned pos = lbase[b] + histW[wave][b] + ((m >> 17) & 0x3FFFu);
            unsigned short hb = __half_as_ushort(__float2half_rn(val));
            stage[pos] = ((m & (APB - 1)) << 16) | (unsigned)hb;
        }
        __syncthreads();                 // stage ready; bcast visible

        // ==== pipeline: issue next chunk's stream loads under copy-out ====
        int cn = (int)bcast;
        if (cn < nchunks) LOAD_STREAMS(cn, rv, wv, srcv, dstv);

        // coalesced copy-out, buckets distributed across the 16 waves
        for (int b = wave; b < nb; b += NW) {
            unsigned cnt = hist[b], lb = lbase[b], gb = gbase[b];
            unsigned* dst = pairs + (size_t)b * (size_t)cap + gb;
            for (unsigned i = lane; i < cnt; i += 64)
                if (gb + i < (unsigned)cap) dst[i] = stage[lb + i];
        }
        ((unsigned*)histW)[tid] = 0u;    // histW dead after phase B
        __syncthreads();                 // orders stage/histW reuse
        c = cn;
    }
}

// ---------------- p1 fallback (per-chunk grid, spc8 global) ----------------
#define TPBF 256
#define NWF  4
#define BLKF (TPBF * EPT)        // 2048
__global__ __launch_bounds__(TPBF) void p1_bin(
    const int* __restrict__ edge_src, const int* __restrict__ edge_dst,
    const float* __restrict__ dist, const float* __restrict__ swt,
    const unsigned char* __restrict__ spc8, const uint4* __restrict__ tab16,
    unsigned* __restrict__ pairs, unsigned* __restrict__ cursor,
    int nb, int cap, int n_edges)
{
    __shared__ unsigned stage[BLKF];
    __shared__ unsigned hist4[NWF][NBMAX];
    __shared__ unsigned hist[NBMAX];
    __shared__ unsigned lbase[NBMAX];
    __shared__ unsigned gbase[NBMAX];

    int tid = threadIdx.x;
    ((unsigned*)hist4)[tid] = 0u;
    __syncthreads();

    int lane = tid & 63, wave = tid >> 6;
    long long wbase = (long long)blockIdx.x * BLKF + (long long)wave * (64 * EPT);

    unsigned meta[EPT];
    unsigned short s12r[EPT];
    {
        int srcv[EPT], dstv[EPT];
        #pragma unroll
        for (int j = 0; j < EPT / 4; ++j) {
            long long e0 = wbase + j * 256 + lane * 4;
            if (e0 + 3 < (long long)n_edges) {
                ivec4 s4 = *reinterpret_cast<const ivec4*>(edge_src + e0);
                ivec4 d4 = *reinterpret_cast<const ivec4*>(edge_dst + e0);
                #pragma unroll
                for (int k = 0; k < 4; ++k) { srcv[j*4+k] = s4[k]; dstv[j*4+k] = d4[k]; }
            } else {
                #pragma unroll
                for (int k = 0; k < 4; ++k) {
                    long long e = e0 + k;
                    bool v = (e < (long long)n_edges);
                    srcv[j*4+k] = v ? edge_src[e] : 0;
                    dstv[j*4+k] = v ? edge_dst[e] : 0;
                }
            }
        }
        int ssv[EPT], sdv[EPT];
        #pragma unroll
        for (int i = 0; i < EPT; ++i) ssv[i] = spc8[srcv[i]];
        #pragma unroll
        for (int i = 0; i < EPT; ++i) sdv[i] = spc8[dstv[i]];
        #pragma unroll
        for (int j = 0; j < EPT / 4; ++j) {
            long long e0 = wbase + j * 256 + lane * 4;
            #pragma unroll
            for (int k = 0; k < 4; ++k) {
                int idx = j * 4 + k;
                s12r[idx] = (unsigned short)(ssv[idx] + TAB93 * sdv[idx]);
                meta[idx] = 0u;
                if (e0 + k < (long long)n_edges) {
                    unsigned b    = (unsigned)srcv[idx] >> APB_LOG;
                    unsigned lsrc = (unsigned)srcv[idx] & (APB - 1);
                    unsigned rank = atomicAdd(&hist4[wave][b], 1u);
                    meta[idx] = 0x80000000u | (rank << 17) | (b << 11) | lsrc;
                }
            }
        }
    }
    __syncthreads();
    if (tid < 64) {
        unsigned run = 0;
        #pragma unroll
        for (int w = 0; w < NWF; ++w) {
            unsigned t = hist4[w][tid];
            hist4[w][tid] = run;
            run += t;
        }
        unsigned tot = run;
        if (tid < nb) hist[tid] = tot;
        unsigned v = (tid < nb) ? tot : 0u;
        unsigned x = v;
        #pragma unroll
        for (int off = 1; off < 64; off <<= 1) {
            unsigned y = __shfl_up(x, off);
            if ((tid & 63) >= off) x += y;
        }
        if (tid < nb) {
            lbase[tid] = x - v;
            gbase[tid] = v ? atomicAdd(cursor + tid, v) : 0u;
        }
    }
    __syncthreads();
    {
        long long eA = wbase + lane * 4;
        long long eB = wbase + 256 + lane * 4;
        float rA[4], wA[4], rB[4], wB[4];
        bool fullB = (eB + 3 < (long long)n_edges);
        if (fullB) {
            fvec4 r4 = *reinterpret_cast<const fvec4*>(dist + eA);
            fvec4 w4 = *reinterpret_cast<const fvec4*>(swt + eA);
            fvec4 r5 = *reinterpret_cast<const fvec4*>(dist + eB);
            fvec4 w5 = *reinterpret_cast<const fvec4*>(swt + eB);
            #pragma unroll
            for (int k = 0; k < 4; ++k) {
                rA[k] = r4[k]; wA[k] = w4[k]; rB[k] = r5[k]; wB[k] = w5[k];
            }
        } else {
            #pragma unroll
            for (int k = 0; k < 4; ++k) {
                long long ea = eA + k, eb = eB + k;
                bool va = (ea < (long long)n_edges), vb = (eb < (long long)n_edges);
                rA[k] = va ? dist[ea] : 1.f;  wA[k] = va ? swt[ea] : 0.f;
                rB[k] = vb ? dist[eb] : 1.f;  wB[k] = vb ? swt[eb] : 0.f;
            }
        }
        uint4 tA[4], tB[4];
        #pragma unroll
        for (int k = 0; k < 4; ++k) tA[k] = tab16[s12r[k]];
        #pragma unroll
        for (int k = 0; k < 4; ++k) tB[k] = tab16[s12r[4 + k]];
        #pragma unroll
        for (int g = 0; g < 2; ++g) {
            const float* r = g ? rB : rA;
            const float* w = g ? wB : wA;
            const uint4* t = g ? tB : tA;
            #pragma unroll
            for (int k = 0; k < 4; ++k) {
                int idx = g * 4 + k;
                unsigned m = meta[idx];
                if (!(m & 0x80000000u)) continue;
                float c0 = half_lo(t[k].x), c1 = half_hi(t[k].x);
                float c2 = half_lo(t[k].y), na0 = half_hi(t[k].y);
                float na1 = half_lo(t[k].z), na2 = half_hi(t[k].z);
                float phi = c0 * __expf(na0 * r[k])
                          + c1 * __expf(na1 * r[k])
                          + c2 * __expf(na2 * r[k]);
                float val = HALF_BOHR * phi * w[k] * FAST_RCP(r[k]);
                unsigned b = (m >> 11) & 63u;
                unsigned pos = lbase[b] + hist4[wave][b] + ((m >> 17) & 0x3FFFu);
                unsigned short hb = __half_as_ushort(__float2half_rn(val));
                stage[pos] = ((m & (APB - 1)) << 16) | (unsigned)hb;
            }
        }
    }
    __syncthreads();
    for (int b = wave; b < nb; b += NWF) {
        unsigned cnt = hist[b], lb = lbase[b], gb = gbase[b];
        unsigned* dst = pairs + (size_t)b * (size_t)cap + gb;
        for (unsigned i = lane; i < cnt; i += 64)
            if (gb + i < (unsigned)cap) dst[i] = stage[lb + i];
    }
}

// ---------------- p2a: per-bucket-slice LDS accumulation -> atomic into out --
__global__ __launch_bounds__(TPB2) void p2a_reduce(
    const unsigned* __restrict__ pairs, const unsigned* __restrict__ cursor,
    float* __restrict__ out, int cap, int n_atoms)
{
    int b = blockIdx.x / SPLITS;
    int s = blockIdx.x % SPLITS;
    __shared__ float acc[APB];
    for (int i = threadIdx.x; i < APB; i += TPB2) acc[i] = 0.f;
    __syncthreads();
    unsigned cnt = cursor[b];
    if (cnt > (unsigned)cap) cnt = (unsigned)cap;
    unsigned nq = (cnt + 3u) >> 2;
    unsigned qb = (unsigned)((unsigned long long)nq * s / SPLITS);
    unsigned qe = (unsigned)((unsigned long long)nq * (s + 1) / SPLITS);
    const uint4* p4 = (const uint4*)(pairs + (size_t)b * (size_t)cap);
    for (unsigned q = qb + threadIdx.x; q < qe; q += TPB2) {
        uint4 v = p4[q];
        unsigned base = q << 2;
        if (base + 3u < cnt) {
            unsafeAtomicAdd(&acc[v.x >> 16], __half2float(__ushort_as_half((unsigned short)(v.x & 0xFFFFu))));
            unsafeAtomicAdd(&acc[v.y >> 16], __half2float(__ushort_as_half((unsigned short)(v.y & 0xFFFFu))));
            unsafeAtomicAdd(&acc[v.z >> 16], __half2float(__ushort_as_half((unsigned short)(v.z & 0xFFFFu))));
            unsafeAtomicAdd(&acc[v.w >> 16], __half2float(__ushort_as_half((unsigned short)(v.w & 0xFFFFu))));
        } else {
            unsigned vv[4] = {v.x, v.y, v.z, v.w};
            #pragma unroll
            for (int e = 0; e < 4; ++e)
                if (base + (unsigned)e < cnt)
                    unsafeAtomicAdd(&acc[vv[e] >> 16],
                        __half2float(__ushort_as_half((unsigned short)(vv[e] & 0xFFFFu))));
        }
    }
    __syncthreads();
    int abase = b * APB;
    for (int k = threadIdx.x; k < APB; k += TPB2) {
        int atom = abase + k;
        float vv = acc[k];
        if (atom < n_atoms && vv != 0.0f)
            unsafeAtomicAdd(&out[atom], vv);
    }
}

// ---------------- fallback: direct device atomics, no prep ----------------
__global__ __launch_bounds__(TPB2) void erep_edges_direct(
    const int* __restrict__ edge_src, const int* __restrict__ edge_dst,
    const float* __restrict__ dist, const float* __restrict__ swt,
    const int* __restrict__ species, const float* __restrict__ CS,
    const float* __restrict__ ALPHAS, float* __restrict__ out, int n_edges)
{
    int e = blockIdx.x * TPB2 + threadIdx.x;
    if (e >= n_edges) return;
    int ss = species[edge_src[e]], sd = species[edge_dst[e]];
    int prod = ss * sd;
    if (prod == 0) return;
    int s12 = ss + ZMAX_C * sd;
    float r = dist[e];
    float phi = CS[3*s12+0] * __expf(-ALPHAS[3*s12+0] * r)
              + CS[3*s12+1] * __expf(-ALPHAS[3*s12+1] * r)
              + CS[3*s12+2] * __expf(-ALPHAS[3*s12+2] * r);
    atomicAdd(out + edge_src[e],
              HALF_BOHR * (float)prod * phi * swt[e] * FAST_RCP(r));
}

// ============================ launcher ======================================
extern "C" void kernel_launch(void* const* d_in, const int* in_sizes, int n_in,
                              void* d_out, int out_size, void* d_ws, size_t ws_size,
                              hipStream_t stream)
{
    const int*   species  = (const int*)  d_in[0];
    const int*   edge_src = (const int*)  d_in[1];
    const int*   edge_dst = (const int*)  d_in[2];
    const float* dist     = (const float*)d_in[3];
    const float* swt      = (const float*)d_in[4];
    const float* CS       = (const float*)d_in[5];
    const float* ALPHAS   = (const float*)d_in[6];
    float* out = (float*)d_out;

    int n_atoms = in_sizes[0];
    int n_edges = in_sizes[1];

    int nb = (n_atoms + APB - 1) / APB;
    long long capll = (long long)n_edges / nb + (long long)n_edges / ((long long)nb * 32) + 256;
    int cap = (int)((capll + 31) & ~31LL);

    size_t pairs_sz = ((size_t)nb * (size_t)cap * 4 + 255) & ~(size_t)255;
    size_t cur_sz   = ((size_t)nb * 4 + 255) & ~(size_t)255;
    size_t tab_sz   = ((size_t)NTAB * 16 + 255) & ~(size_t)255;
    size_t spc_sz   = ((size_t)n_atoms + 255) & ~(size_t)255;
    size_t syn_sz   = 256;
    size_t need = pairs_sz + cur_sz + tab_sz + spc_sz + syn_sz;

    if (nb <= NBMAX && n_edges > 0 && ws_size >= need) {
        char* w = (char*)d_ws;
        unsigned*       pairs   = (unsigned*)w;
        unsigned*       cursor  = (unsigned*)(w + pairs_sz);
        uint4*          tab16   = (uint4*)(w + pairs_sz + cur_sz);
        unsigned char*  spc8    = (unsigned char*)(w + pairs_sz + cur_sz + tab_sz);
        unsigned*       steal   = (unsigned*)(w + pairs_sz + cur_sz + tab_sz + spc_sz);

        int pmax = n_atoms > NTAB ? n_atoms : NTAB;
        p0_prep<<<(pmax + TPB2 - 1) / TPB2, TPB2, 0, stream>>>(
            CS, ALPHAS, species, tab16, spc8, cursor, steal, out, n_atoms, nb);

        if (n_atoms <= SPC_CAP) {
            // persistent p1: 1 block/CU (157 KB LDS), spc8 cached in LDS,
            // work-stolen chunks (first chunk = bid; steal offset by G)
            int dev = 0, ncu = 256;
            (void)hipGetDevice(&dev);
            (void)hipDeviceGetAttribute(&ncu, hipDeviceAttributeMultiprocessorCount, dev);
            int nchunks = (int)(((long long)n_edges + BLK_EDGES - 1) / BLK_EDGES);
            int G = ncu > 0 ? ncu : 256;
            if (G > nchunks) G = nchunks;
            p1_bin_lds<<<G, TPB, 0, stream>>>(
                edge_src, edge_dst, dist, swt, spc8, tab16,
                pairs, cursor, steal, nb, cap, n_edges, n_atoms, nchunks);
        } else {
            p1_bin<<<(n_edges + BLKF - 1) / BLKF, TPBF, 0, stream>>>(
                edge_src, edge_dst, dist, swt, spc8, tab16,
                pairs, cursor, nb, cap, n_edges);
        }

        p2a_reduce<<<nb * SPLITS, TPB2, 0, stream>>>(pairs, cursor, out, cap, n_atoms);
    } else {
        (void)hipMemsetAsync(d_out, 0, (size_t)out_size * sizeof(float), stream);
        erep_edges_direct<<<(n_edges + TPB2 - 1) / TPB2, TPB2, 0, stream>>>(
            edge_src, edge_dst, dist, swt, species, CS, ALPHAS, out, n_edges);
    }
}

// Round 11
// 208.166 us; speedup vs baseline: 1.0123x; 1.0123x over previous
//
#include <hip/hip_runtime.h>
#include <hip/hip_fp16.h>

// RepulsionNLH: erep_atomic[a] = 0.5*BOHR * sum_{e: src[e]==a} Z[src]*Z[dst]*phi(e)*switch[e]/dist[e]
// phi(e) = sum_k CS[s12][k] * exp(-ALPHAS[s12][k] * dist[e]),  s12 = species[src] + 92*species[dst]
//
// R23: R22 was a canceled bundle -- the cross-chunk pipeline REGRESSED p1
// (61 -> 75us: next-chunk stream regs held live across copy-out + bcast
// dependency spanning two barriers), while SPLITS 16->32 improved p2a ~14us
// (total flat). Unbundle: revert p1 to the R21 body exactly (loop-head steal,
// in-chunk hoisted loads = the proven 61us config), KEEP SPLITS=32.

#define ZMAX_C 92
#define TAB93  93
#define NTAB   (TAB93 * TAB93)   // 8649
#define HALF_BOHR 0.264588605f   // 0.5 * 0.52917721
#define NBMAX 64
#define APB 2048                 // atoms per bucket
#define APB_LOG 11
#define SPLITS 32
#define TPB  1024                // persistent p1 block size (16 waves)
#define NW   (TPB / 64)          // 16 waves
#define TPB2 256                 // p0/p2a block size
#define EPT 8                    // edges per thread in p1
#define BLK_EDGES (TPB * EPT)    // 8192 edges per chunk
#define SPC_CAP 122880           // 120 KB LDS species cache cap

typedef int            ivec4 __attribute__((ext_vector_type(4)));
typedef float          fvec4 __attribute__((ext_vector_type(4)));

#if __has_builtin(__builtin_amdgcn_rcpf)
#define FAST_RCP(x) __builtin_amdgcn_rcpf(x)
#else
#define FAST_RCP(x) (1.0f / (x))
#endif

__device__ __forceinline__ float half_lo(unsigned u) {
    return __half2float(*reinterpret_cast<const __half*>(&u));
}
__device__ __forceinline__ float half_hi(unsigned u) {
    unsigned s = u >> 16;
    return __half2float(*reinterpret_cast<const __half*>(&s));
}

// ---------------- p0: Z-premult f16 table, spc8 bytes, cursors, out zero ----
__global__ __launch_bounds__(TPB2) void p0_prep(
    const float* __restrict__ CS, const float* __restrict__ ALPHAS,
    const int* __restrict__ species,
    uint4* __restrict__ tab16, unsigned char* __restrict__ spc8,
    unsigned* __restrict__ cursor, unsigned* __restrict__ steal,
    float* __restrict__ out, int n_atoms, int nb)
{
    int i = blockIdx.x * TPB2 + threadIdx.x;
    if (i < NTAB) {
        int sd = i / TAB93;
        int ss = i - TAB93 * sd;
        int ref = ss + ZMAX_C * sd;          // reference's (colliding) index
        float Z = (ss > 0 && sd > 0) ? (float)(ss * sd) : 0.0f;
        __half h[8];
        h[0] = __float2half_rn(CS[3*ref+0] * Z);
        h[1] = __float2half_rn(CS[3*ref+1] * Z);
        h[2] = __float2half_rn(CS[3*ref+2] * Z);
        h[3] = __float2half_rn(-ALPHAS[3*ref+0]);
        h[4] = __float2half_rn(-ALPHAS[3*ref+1]);
        h[5] = __float2half_rn(-ALPHAS[3*ref+2]);
        h[6] = __half(0.0f); h[7] = __half(0.0f);
        tab16[i] = *reinterpret_cast<uint4*>(h);
    }
    if (i < n_atoms) {
        spc8[i] = (unsigned char)species[i];
        out[i] = 0.0f;
    }
    if (i < nb) cursor[i] = 0u;
    if (i == 0) *steal = 0u;
}

// ---------------- p1 (persistent, spc8 in LDS, hoisted loads, stealing) -----
// R21 body verbatim: steal at loop-head, all loads hoisted within the chunk.
__global__ __launch_bounds__(TPB) void p1_bin_lds(
    const int* __restrict__ edge_src, const int* __restrict__ edge_dst,
    const float* __restrict__ dist, const float* __restrict__ swt,
    const unsigned char* __restrict__ spc8, const uint4* __restrict__ tab16,
    unsigned* __restrict__ pairs, unsigned* __restrict__ cursor,
    unsigned* __restrict__ steal,
    int nb, int cap, int n_edges, int n_atoms, int nchunks)
{
    __shared__ unsigned char spcL[SPC_CAP];  // 120 KB species cache
    __shared__ unsigned stage[BLK_EDGES];    // 32 KB packed {lsrc<<16 | f16}
    __shared__ unsigned histW[NW][NBMAX];    // 4 KB per-wave histogram replicas
    __shared__ unsigned hist[NBMAX];
    __shared__ unsigned lbase[NBMAX];
    __shared__ unsigned gbase[NBMAX];
    __shared__ unsigned bcast;

    int tid = threadIdx.x;
    int lane = tid & 63, wave = tid >> 6;

    // one-time: species bytes global -> LDS (uint4, ~25 loads/thread)
    {
        uint4* dv = (uint4*)spcL;
        const uint4* sv = (const uint4*)spc8;       // buffer 256B-aligned/padded
        int n16 = (n_atoms + 15) >> 4;
        for (int i = tid; i < n16; i += TPB) dv[i] = sv[i];
    }
    __syncthreads();

    for (;;) {
        if (tid == 0) bcast = atomicAdd(steal, 1u);
        ((unsigned*)histW)[tid] = 0u;        // NW*NBMAX == TPB: one slot each
        __syncthreads();
        int c = (int)bcast;
        if (c >= nchunks) break;

        long long wbase = (long long)c * BLK_EDGES + (long long)wave * (64 * EPT);
        unsigned meta[EPT];   // bit31 valid | rank<<17 | b<<11 | lsrc (rank per-wave, <512)
        unsigned short s12r[EPT];

        // ==== hoisted global loads: everything in flight before phase A ====
        float rv[EPT], wv[EPT];
        {
            long long eA = wbase + lane * 4;
            long long eB = wbase + 256 + lane * 4;
            bool fullB = (eB + 3 < (long long)n_edges);
            if (fullB) {
                fvec4 r4 = *reinterpret_cast<const fvec4*>(dist + eA);
                fvec4 w4 = *reinterpret_cast<const fvec4*>(swt + eA);
                fvec4 r5 = *reinterpret_cast<const fvec4*>(dist + eB);
                fvec4 w5 = *reinterpret_cast<const fvec4*>(swt + eB);
                #pragma unroll
                for (int k = 0; k < 4; ++k) {
                    rv[k] = r4[k];     wv[k] = w4[k];
                    rv[4 + k] = r5[k]; wv[4 + k] = w5[k];
                }
            } else {
                #pragma unroll
                for (int k = 0; k < 4; ++k) {
                    long long ea = eA + k, eb = eB + k;
                    bool va = (ea < (long long)n_edges), vb = (eb < (long long)n_edges);
                    rv[k] = va ? dist[ea] : 1.f;      wv[k] = va ? swt[ea] : 0.f;
                    rv[4 + k] = vb ? dist[eb] : 1.f;  wv[4 + k] = vb ? swt[eb] : 0.f;
                }
            }
        }
        int srcv[EPT], dstv[EPT];
        #pragma unroll
        for (int j = 0; j < EPT / 4; ++j) {
            long long e0 = wbase + j * 256 + lane * 4;
            if (e0 + 3 < (long long)n_edges) {
                ivec4 s4 = *reinterpret_cast<const ivec4*>(edge_src + e0);
                ivec4 d4 = *reinterpret_cast<const ivec4*>(edge_dst + e0);
                #pragma unroll
                for (int k = 0; k < 4; ++k) { srcv[j*4+k] = s4[k]; dstv[j*4+k] = d4[k]; }
            } else {
                #pragma unroll
                for (int k = 0; k < 4; ++k) {
                    long long e = e0 + k;
                    bool v = (e < (long long)n_edges);
                    srcv[j*4+k] = v ? edge_src[e] : 0;
                    dstv[j*4+k] = v ? edge_dst[e] : 0;
                }
            }
        }
        {
            int ssv[EPT], sdv[EPT];
            #pragma unroll
            for (int i = 0; i < EPT; ++i) ssv[i] = spcL[srcv[i]];
            #pragma unroll
            for (int i = 0; i < EPT; ++i) sdv[i] = spcL[dstv[i]];
            #pragma unroll
            for (int i = 0; i < EPT; ++i)
                s12r[i] = (unsigned short)(ssv[i] + TAB93 * sdv[i]);
        }
        uint4 tv[EPT];
        #pragma unroll
        for (int k = 0; k < EPT; ++k) tv[k] = tab16[s12r[k]];

        // ==== phase A: bin (hist atomics overlap the tab gathers in flight) ====
        #pragma unroll
        for (int j = 0; j < EPT / 4; ++j) {
            long long e0 = wbase + j * 256 + lane * 4;
            #pragma unroll
            for (int k = 0; k < 4; ++k) {
                int idx = j * 4 + k;
                meta[idx] = 0u;
                if (e0 + k < (long long)n_edges) {
                    unsigned b    = (unsigned)srcv[idx] >> APB_LOG;
                    unsigned lsrc = (unsigned)srcv[idx] & (APB - 1);
                    unsigned rank = atomicAdd(&histW[wave][b], 1u);   // < 512
                    meta[idx] = 0x80000000u | (rank << 17) | (b << 11) | lsrc;
                }
            }
        }
        __syncthreads();
        // fold wave replicas into totals + per-wave offsets; scan; reserve
        if (tid < 64) {
            unsigned run = 0;
            #pragma unroll
            for (int w = 0; w < NW; ++w) {
                unsigned t = histW[w][tid];
                histW[w][tid] = run;
                run += t;
            }
            unsigned tot = run;
            if (tid < nb) hist[tid] = tot;
            unsigned v = (tid < nb) ? tot : 0u;
            unsigned x = v;
            #pragma unroll
            for (int off = 1; off < 64; off <<= 1) {
                unsigned y = __shfl_up(x, off);
                if ((tid & 63) >= off) x += y;
            }
            if (tid < nb) {
                lbase[tid] = x - v;
                gbase[tid] = v ? atomicAdd(cursor + tid, v) : 0u;
            }
        }
        __syncthreads();

        // ==== phase B: pure compute + scatter (all operands in registers) ====
        #pragma unroll
        for (int idx = 0; idx < EPT; ++idx) {
            unsigned m = meta[idx];
            if (!(m & 0x80000000u)) continue;
            float c0 = half_lo(tv[idx].x), c1 = half_hi(tv[idx].x);
            float c2 = half_lo(tv[idx].y), na0 = half_hi(tv[idx].y);
            float na1 = half_lo(tv[idx].z), na2 = half_hi(tv[idx].z);
            float r = rv[idx];
            float phi = c0 * __expf(na0 * r)
                      + c1 * __expf(na1 * r)
                      + c2 * __expf(na2 * r);
            float val = HALF_BOHR * phi * wv[idx] * FAST_RCP(r);  // Z premult in c
            unsigned b = (m >> 11) & 63u;
            unsigned pos = lbase[b] + histW[wave][b] + ((m >> 17) & 0x3FFFu);
            unsigned short hb = __half_as_ushort(__float2half_rn(val));
            stage[pos] = ((m & (APB - 1)) << 16) | (unsigned)hb;
        }
        __syncthreads();
        // coalesced copy-out, buckets distributed across the 16 waves
        for (int b = wave; b < nb; b += NW) {
            unsigned cnt = hist[b], lb = lbase[b], gb = gbase[b];
            unsigned* dst = pairs + (size_t)b * (size_t)cap + gb;
            for (unsigned i = lane; i < cnt; i += 64)
                if (gb + i < (unsigned)cap) dst[i] = stage[lb + i];
        }
        // loop-head histW zero + __syncthreads orders stage/hist reuse
    }
}

// ---------------- p1 fallback (per-chunk grid, spc8 global) ----------------
#define TPBF 256
#define NWF  4
#define BLKF (TPBF * EPT)        // 2048
__global__ __launch_bounds__(TPBF) void p1_bin(
    const int* __restrict__ edge_src, const int* __restrict__ edge_dst,
    const float* __restrict__ dist, const float* __restrict__ swt,
    const unsigned char* __restrict__ spc8, const uint4* __restrict__ tab16,
    unsigned* __restrict__ pairs, unsigned* __restrict__ cursor,
    int nb, int cap, int n_edges)
{
    __shared__ unsigned stage[BLKF];
    __shared__ unsigned hist4[NWF][NBMAX];
    __shared__ unsigned hist[NBMAX];
    __shared__ unsigned lbase[NBMAX];
    __shared__ unsigned gbase[NBMAX];

    int tid = threadIdx.x;
    ((unsigned*)hist4)[tid] = 0u;
    __syncthreads();

    int lane = tid & 63, wave = tid >> 6;
    long long wbase = (long long)blockIdx.x * BLKF + (long long)wave * (64 * EPT);

    unsigned meta[EPT];
    unsigned short s12r[EPT];
    {
        int srcv[EPT], dstv[EPT];
        #pragma unroll
        for (int j = 0; j < EPT / 4; ++j) {
            long long e0 = wbase + j * 256 + lane * 4;
            if (e0 + 3 < (long long)n_edges) {
                ivec4 s4 = *reinterpret_cast<const ivec4*>(edge_src + e0);
                ivec4 d4 = *reinterpret_cast<const ivec4*>(edge_dst + e0);
                #pragma unroll
                for (int k = 0; k < 4; ++k) { srcv[j*4+k] = s4[k]; dstv[j*4+k] = d4[k]; }
            } else {
                #pragma unroll
                for (int k = 0; k < 4; ++k) {
                    long long e = e0 + k;
                    bool v = (e < (long long)n_edges);
                    srcv[j*4+k] = v ? edge_src[e] : 0;
                    dstv[j*4+k] = v ? edge_dst[e] : 0;
                }
            }
        }
        int ssv[EPT], sdv[EPT];
        #pragma unroll
        for (int i = 0; i < EPT; ++i) ssv[i] = spc8[srcv[i]];
        #pragma unroll
        for (int i = 0; i < EPT; ++i) sdv[i] = spc8[dstv[i]];
        #pragma unroll
        for (int j = 0; j < EPT / 4; ++j) {
            long long e0 = wbase + j * 256 + lane * 4;
            #pragma unroll
            for (int k = 0; k < 4; ++k) {
                int idx = j * 4 + k;
                s12r[idx] = (unsigned short)(ssv[idx] + TAB93 * sdv[idx]);
                meta[idx] = 0u;
                if (e0 + k < (long long)n_edges) {
                    unsigned b    = (unsigned)srcv[idx] >> APB_LOG;
                    unsigned lsrc = (unsigned)srcv[idx] & (APB - 1);
                    unsigned rank = atomicAdd(&hist4[wave][b], 1u);
                    meta[idx] = 0x80000000u | (rank << 17) | (b << 11) | lsrc;
                }
            }
        }
    }
    __syncthreads();
    if (tid < 64) {
        unsigned run = 0;
        #pragma unroll
        for (int w = 0; w < NWF; ++w) {
            unsigned t = hist4[w][tid];
            hist4[w][tid] = run;
            run += t;
        }
        unsigned tot = run;
        if (tid < nb) hist[tid] = tot;
        unsigned v = (tid < nb) ? tot : 0u;
        unsigned x = v;
        #pragma unroll
        for (int off = 1; off < 64; off <<= 1) {
            unsigned y = __shfl_up(x, off);
            if ((tid & 63) >= off) x += y;
        }
        if (tid < nb) {
            lbase[tid] = x - v;
            gbase[tid] = v ? atomicAdd(cursor + tid, v) : 0u;
        }
    }
    __syncthreads();
    {
        long long eA = wbase + lane * 4;
        long long eB = wbase + 256 + lane * 4;
        float rA[4], wA[4], rB[4], wB[4];
        bool fullB = (eB + 3 < (long long)n_edges);
        if (fullB) {
            fvec4 r4 = *reinterpret_cast<const fvec4*>(dist + eA);
            fvec4 w4 = *reinterpret_cast<const fvec4*>(swt + eA);
            fvec4 r5 = *reinterpret_cast<const fvec4*>(dist + eB);
            fvec4 w5 = *reinterpret_cast<const fvec4*>(swt + eB);
            #pragma unroll
            for (int k = 0; k < 4; ++k) {
                rA[k] = r4[k]; wA[k] = w4[k]; rB[k] = r5[k]; wB[k] = w5[k];
            }
        } else {
            #pragma unroll
            for (int k = 0; k < 4; ++k) {
                long long ea = eA + k, eb = eB + k;
                bool va = (ea < (long long)n_edges), vb = (eb < (long long)n_edges);
                rA[k] = va ? dist[ea] : 1.f;  wA[k] = va ? swt[ea] : 0.f;
                rB[k] = vb ? dist[eb] : 1.f;  wB[k] = vb ? swt[eb] : 0.f;
            }
        }
        uint4 tA[4], tB[4];
        #pragma unroll
        for (int k = 0; k < 4; ++k) tA[k] = tab16[s12r[k]];
        #pragma unroll
        for (int k = 0; k < 4; ++k) tB[k] = tab16[s12r[4 + k]];
        #pragma unroll
        for (int g = 0; g < 2; ++g) {
            const float* r = g ? rB : rA;
            const float* w = g ? wB : wA;
            const uint4* t = g ? tB : tA;
            #pragma unroll
            for (int k = 0; k < 4; ++k) {
                int idx = g * 4 + k;
                unsigned m = meta[idx];
                if (!(m & 0x80000000u)) continue;
                float c0 = half_lo(t[k].x), c1 = half_hi(t[k].x);
                float c2 = half_lo(t[k].y), na0 = half_hi(t[k].y);
                float na1 = half_lo(t[k].z), na2 = half_hi(t[k].z);
                float phi = c0 * __expf(na0 * r[k])
                          + c1 * __expf(na1 * r[k])
                          + c2 * __expf(na2 * r[k]);
                float val = HALF_BOHR * phi * w[k] * FAST_RCP(r[k]);
                unsigned b = (m >> 11) & 63u;
                unsigned pos = lbase[b] + hist4[wave][b] + ((m >> 17) & 0x3FFFu);
                unsigned short hb = __half_as_ushort(__float2half_rn(val));
                stage[pos] = ((m & (APB - 1)) << 16) | (unsigned)hb;
            }
        }
    }
    __syncthreads();
    for (int b = wave; b < nb; b += NWF) {
        unsigned cnt = hist[b], lb = lbase[b], gb = gbase[b];
        unsigned* dst = pairs + (size_t)b * (size_t)cap + gb;
        for (unsigned i = lane; i < cnt; i += 64)
            if (gb + i < (unsigned)cap) dst[i] = stage[lb + i];
    }
}

// ---------------- p2a: per-bucket-slice LDS accumulation -> atomic into out --
__global__ __launch_bounds__(TPB2) void p2a_reduce(
    const unsigned* __restrict__ pairs, const unsigned* __restrict__ cursor,
    float* __restrict__ out, int cap, int n_atoms)
{
    int b = blockIdx.x / SPLITS;
    int s = blockIdx.x % SPLITS;
    __shared__ float acc[APB];
    for (int i = threadIdx.x; i < APB; i += TPB2) acc[i] = 0.f;
    __syncthreads();
    unsigned cnt = cursor[b];
    if (cnt > (unsigned)cap) cnt = (unsigned)cap;
    unsigned nq = (cnt + 3u) >> 2;
    unsigned qb = (unsigned)((unsigned long long)nq * s / SPLITS);
    unsigned qe = (unsigned)((unsigned long long)nq * (s + 1) / SPLITS);
    const uint4* p4 = (const uint4*)(pairs + (size_t)b * (size_t)cap);
    for (unsigned q = qb + threadIdx.x; q < qe; q += TPB2) {
        uint4 v = p4[q];
        unsigned base = q << 2;
        if (base + 3u < cnt) {
            unsafeAtomicAdd(&acc[v.x >> 16], __half2float(__ushort_as_half((unsigned short)(v.x & 0xFFFFu))));
            unsafeAtomicAdd(&acc[v.y >> 16], __half2float(__ushort_as_half((unsigned short)(v.y & 0xFFFFu))));
            unsafeAtomicAdd(&acc[v.z >> 16], __half2float(__ushort_as_half((unsigned short)(v.z & 0xFFFFu))));
            unsafeAtomicAdd(&acc[v.w >> 16], __half2float(__ushort_as_half((unsigned short)(v.w & 0xFFFFu))));
        } else {
            unsigned vv[4] = {v.x, v.y, v.z, v.w};
            #pragma unroll
            for (int e = 0; e < 4; ++e)
                if (base + (unsigned)e < cnt)
                    unsafeAtomicAdd(&acc[vv[e] >> 16],
                        __half2float(__ushort_as_half((unsigned short)(vv[e] & 0xFFFFu))));
        }
    }
    __syncthreads();
    int abase = b * APB;
    for (int k = threadIdx.x; k < APB; k += TPB2) {
        int atom = abase + k;
        float vv = acc[k];
        if (atom < n_atoms && vv != 0.0f)
            unsafeAtomicAdd(&out[atom], vv);
    }
}

// ---------------- fallback: direct device atomics, no prep ----------------
__global__ __launch_bounds__(TPB2) void erep_edges_direct(
    const int* __restrict__ edge_src, const int* __restrict__ edge_dst,
    const float* __restrict__ dist, const float* __restrict__ swt,
    const int* __restrict__ species, const float* __restrict__ CS,
    const float* __restrict__ ALPHAS, float* __restrict__ out, int n_edges)
{
    int e = blockIdx.x * TPB2 + threadIdx.x;
    if (e >= n_edges) return;
    int ss = species[edge_src[e]], sd = species[edge_dst[e]];
    int prod = ss * sd;
    if (prod == 0) return;
    int s12 = ss + ZMAX_C * sd;
    float r = dist[e];
    float phi = CS[3*s12+0] * __expf(-ALPHAS[3*s12+0] * r)
              + CS[3*s12+1] * __expf(-ALPHAS[3*s12+1] * r)
              + CS[3*s12+2] * __expf(-ALPHAS[3*s12+2] * r);
    atomicAdd(out + edge_src[e],
              HALF_BOHR * (float)prod * phi * swt[e] * FAST_RCP(r));
}

// ============================ launcher ======================================
extern "C" void kernel_launch(void* const* d_in, const int* in_sizes, int n_in,
                              void* d_out, int out_size, void* d_ws, size_t ws_size,
                              hipStream_t stream)
{
    const int*   species  = (const int*)  d_in[0];
    const int*   edge_src = (const int*)  d_in[1];
    const int*   edge_dst = (const int*)  d_in[2];
    const float* dist     = (const float*)d_in[3];
    const float* swt      = (const float*)d_in[4];
    const float* CS       = (const float*)d_in[5];
    const float* ALPHAS   = (const float*)d_in[6];
    float* out = (float*)d_out;

    int n_atoms = in_sizes[0];
    int n_edges = in_sizes[1];

    int nb = (n_atoms + APB - 1) / APB;
    long long capll = (long long)n_edges / nb + (long long)n_edges / ((long long)nb * 32) + 256;
    int cap = (int)((capll + 31) & ~31LL);

    size_t pairs_sz = ((size_t)nb * (size_t)cap * 4 + 255) & ~(size_t)255;
    size_t cur_sz   = ((size_t)nb * 4 + 255) & ~(size_t)255;
    size_t tab_sz   = ((size_t)NTAB * 16 + 255) & ~(size_t)255;
    size_t spc_sz   = ((size_t)n_atoms + 255) & ~(size_t)255;
    size_t syn_sz   = 256;
    size_t need = pairs_sz + cur_sz + tab_sz + spc_sz + syn_sz;

    if (nb <= NBMAX && n_edges > 0 && ws_size >= need) {
        char* w = (char*)d_ws;
        unsigned*       pairs   = (unsigned*)w;
        unsigned*       cursor  = (unsigned*)(w + pairs_sz);
        uint4*          tab16   = (uint4*)(w + pairs_sz + cur_sz);
        unsigned char*  spc8    = (unsigned char*)(w + pairs_sz + cur_sz + tab_sz);
        unsigned*       steal   = (unsigned*)(w + pairs_sz + cur_sz + tab_sz + spc_sz);

        int pmax = n_atoms > NTAB ? n_atoms : NTAB;
        p0_prep<<<(pmax + TPB2 - 1) / TPB2, TPB2, 0, stream>>>(
            CS, ALPHAS, species, tab16, spc8, cursor, steal, out, n_atoms, nb);

        if (n_atoms <= SPC_CAP) {
            // persistent p1: 1 block/CU (157 KB LDS), spc8 cached in LDS,
            // work-stolen chunks (skew <= 1 chunk)
            int dev = 0, ncu = 256;
            (void)hipGetDevice(&dev);
            (void)hipDeviceGetAttribute(&ncu, hipDeviceAttributeMultiprocessorCount, dev);
            int nchunks = (int)(((long long)n_edges + BLK_EDGES - 1) / BLK_EDGES);
            int G = ncu > 0 ? ncu : 256;
            if (G > nchunks) G = nchunks;
            p1_bin_lds<<<G, TPB, 0, stream>>>(
                edge_src, edge_dst, dist, swt, spc8, tab16,
                pairs, cursor, steal, nb, cap, n_edges, n_atoms, nchunks);
        } else {
            p1_bin<<<(n_edges + BLKF - 1) / BLKF, TPBF, 0, stream>>>(
                edge_src, edge_dst, dist, swt, spc8, tab16,
                pairs, cursor, nb, cap, n_edges);
        }

        p2a_reduce<<<nb * SPLITS, TPB2, 0, stream>>>(pairs, cursor, out, cap, n_atoms);
    } else {
        (void)hipMemsetAsync(d_out, 0, (size_t)out_size * sizeof(float), stream);
        erep_edges_direct<<<(n_edges + TPB2 - 1) / TPB2, TPB2, 0, stream>>>(
            edge_src, edge_dst, dist, swt, species, CS, ALPHAS, out, n_edges);
    }
}